// Round 1
// baseline (535.205 us; speedup 1.0000x reference)
//
#include <hip/hip_runtime.h>
#include <hip/hip_bf16.h>

// GCN 3-layer: out = A_hat @ (A_hat @ relu(A_hat @ relu(X W1)+b1 ... ) )
// Strategy: per-call CSR build (atomic-free aggregation), f32 LDS-tiled GEMMs.

#define THREADS 256

__global__ void count_edges_kernel(const int* __restrict__ col, int* __restrict__ counts, int E) {
    int e = blockIdx.x * blockDim.x + threadIdx.x;
    if (e < E) atomicAdd(&counts[col[e]], 1);
}

__global__ void dinv_kernel(const int* __restrict__ counts, float* __restrict__ dinv, int n) {
    int i = blockIdx.x * blockDim.x + threadIdx.x;
    if (i < n) {
        float deg = (float)(counts[i] + 1);  // +1 self loop
        dinv[i] = rsqrtf(deg);
    }
}

// Single-block exclusive scan over counts[n] -> offsets[n], offsets[n]=total. Also zeroes cursor.
__global__ void scan_kernel(const int* __restrict__ counts, int* __restrict__ offsets,
                            int* __restrict__ cursor, int n) {
    __shared__ int wsum[16];
    int tid = threadIdx.x;
    int lane = tid & 63, wid = tid >> 6;
    int running = 0;
    for (int base = 0; base < n; base += 1024) {
        int i = base + tid;
        int c = (i < n) ? counts[i] : 0;
        int v = c;
        #pragma unroll
        for (int d = 1; d < 64; d <<= 1) {
            int u = __shfl_up(v, d);
            if (lane >= d) v += u;
        }
        if (lane == 63) wsum[wid] = v;
        __syncthreads();
        if (tid < 16) {
            int s = wsum[tid];
            #pragma unroll
            for (int d = 1; d < 16; d <<= 1) {
                int u = __shfl_up(s, d);
                if (tid >= d) s += u;
            }
            wsum[tid] = s;
        }
        __syncthreads();
        int woff = (wid == 0) ? 0 : wsum[wid - 1];
        int incl = v + woff;
        if (i < n) {
            offsets[i] = running + incl - c;
            cursor[i] = 0;
        }
        running += wsum[15];
        __syncthreads();
    }
    if (tid == 0) offsets[n] = running;
}

__global__ void fill_csr_kernel(const int* __restrict__ row, const int* __restrict__ col,
                                const int* __restrict__ offsets, int* __restrict__ cursor,
                                const float* __restrict__ dinv,
                                int* __restrict__ srcs, float* __restrict__ wnorm, int E) {
    int e = blockIdx.x * blockDim.x + threadIdx.x;
    if (e < E) {
        int c = col[e];
        int r = row[e];
        int pos = offsets[c] + atomicAdd(&cursor[c], 1);
        srcs[pos] = r;
        wnorm[pos] = dinv[r] * dinv[c];
    }
}

// out[n, DO] = A[n,128] @ W[128, DO]   (no bias/act; those are fused into aggregation)
// 256 threads, 64 rows/block. Each thread: RPT rows x 8 cols register tile.
template <int DO>
__global__ __launch_bounds__(256) void gemm_kernel(const float* __restrict__ A,
                                                   const float* __restrict__ W,
                                                   float* __restrict__ out, int n) {
    constexpr int K = 128;
    constexpr int BR = 64;
    constexpr int LDA = K + 4;             // pad: bank-conflict-free A reads
    constexpr int COLTH = DO / 8;          // 16 (DO=128) or 8 (DO=64)
    constexpr int ROWTH = 256 / COLTH;     // 16 or 32
    constexpr int RPT = BR / ROWTH;        // 4 or 2

    __shared__ float Wl[K * DO];
    __shared__ float Al[BR * LDA];

    int tid = threadIdx.x;
    int rb = blockIdx.x * BR;

    // stage W (row-major [K][DO])
    for (int q = tid; q < K * DO / 4; q += 256) {
        ((float4*)Wl)[q] = ((const float4*)W)[q];
    }
    // stage A tile [BR][K] with padded stride
    for (int q = tid; q < BR * K / 4; q += 256) {
        int r = q >> 5;          // K/4 = 32 float4 per row
        int kq = q & 31;
        int row = rb + r;
        float4 v;
        if (row < n) v = ((const float4*)(A + (size_t)row * K))[kq];
        else { v.x = v.y = v.z = v.w = 0.f; }
        *(float4*)(Al + r * LDA + kq * 4) = v;
    }
    __syncthreads();

    int ct = tid % COLTH;   // cols ct*8 .. ct*8+7
    int rt = tid / COLTH;   // rows rt + ROWTH*i

    float4 acc0[RPT], acc1[RPT];
    #pragma unroll
    for (int i = 0; i < RPT; ++i) {
        acc0[i].x = acc0[i].y = acc0[i].z = acc0[i].w = 0.f;
        acc1[i].x = acc1[i].y = acc1[i].z = acc1[i].w = 0.f;
    }

    #pragma unroll 8
    for (int k = 0; k < K; ++k) {
        float4 w0 = *(const float4*)(Wl + k * DO + ct * 8);
        float4 w1 = *(const float4*)(Wl + k * DO + ct * 8 + 4);
        #pragma unroll
        for (int i = 0; i < RPT; ++i) {
            float a = Al[(rt + ROWTH * i) * LDA + k];
            acc0[i].x += a * w0.x; acc0[i].y += a * w0.y;
            acc0[i].z += a * w0.z; acc0[i].w += a * w0.w;
            acc1[i].x += a * w1.x; acc1[i].y += a * w1.y;
            acc1[i].z += a * w1.z; acc1[i].w += a * w1.w;
        }
    }

    #pragma unroll
    for (int i = 0; i < RPT; ++i) {
        int row = rb + rt + ROWTH * i;
        if (row < n) {
            *(float4*)(out + (size_t)row * DO + ct * 8) = acc0[i];
            *(float4*)(out + (size_t)row * DO + ct * 8 + 4) = acc1[i];
        }
    }
}

// Aggregation: out[d] = bias + hw[d]*dinv[d]^2 + sum_{e in CSR[d]} hw[srcs[e]] * wnorm[e]
// block = 256 threads = (256/DO) dests x DO col-threads
template <int DO, bool RELU>
__global__ __launch_bounds__(256) void agg_kernel(const float* __restrict__ hw,
                                                  const int* __restrict__ offsets,
                                                  const int* __restrict__ srcs,
                                                  const float* __restrict__ wnorm,
                                                  const float* __restrict__ dinv,
                                                  const float* __restrict__ bias,
                                                  float* __restrict__ out, int n) {
    constexpr int DPB = 256 / DO;
    int d = blockIdx.x * DPB + threadIdx.x / DO;
    int j = threadIdx.x % DO;
    if (d >= n) return;
    int beg = offsets[d];
    int end = offsets[d + 1];
    float di = dinv[d];
    float acc = bias[j] + hw[(size_t)d * DO + j] * (di * di);
    for (int e = beg; e < end; ++e) {
        int s = srcs[e];
        float w = wnorm[e];
        acc += hw[(size_t)s * DO + j] * w;
    }
    if (RELU) acc = fmaxf(acc, 0.f);
    out[(size_t)d * DO + j] = acc;
}

extern "C" void kernel_launch(void* const* d_in, const int* in_sizes, int n_in,
                              void* d_out, int out_size, void* d_ws, size_t ws_size,
                              hipStream_t stream) {
    const float* x  = (const float*)d_in[0];
    const float* W1 = (const float*)d_in[1];
    const float* b1 = (const float*)d_in[2];
    const float* W2 = (const float*)d_in[3];
    const float* b2 = (const float*)d_in[4];
    const float* W3 = (const float*)d_in[5];
    const float* b3 = (const float*)d_in[6];
    const int*   ei = (const int*)d_in[7];

    const int N = in_sizes[0] / 128;
    const int E = in_sizes[7] / 2;
    const int* rowi = ei;       // edge_index[0] = sources
    const int* coli = ei + E;   // edge_index[1] = targets

    float* out = (float*)d_out;

    // workspace carve-up (256B aligned)
    char* ws = (char*)d_ws;
    size_t off = 0;
    auto alloc = [&](size_t bytes) -> void* {
        void* p = ws + off;
        off = (off + bytes + 255) & ~(size_t)255;
        return p;
    };
    float* dinv    = (float*)alloc((size_t)N * 4);
    int*   counts  = (int*)  alloc((size_t)N * 4);
    int*   offsets = (int*)  alloc((size_t)(N + 1) * 4);
    int*   cursor  = (int*)  alloc((size_t)N * 4);
    int*   srcs    = (int*)  alloc((size_t)E * 4);
    float* wnorm   = (float*)alloc((size_t)E * 4);
    float* bufA    = (float*)alloc((size_t)N * 128 * 4);
    float* bufB    = (float*)alloc((size_t)N * 128 * 4);

    // ---- degree / norm / CSR ----
    hipMemsetAsync(counts, 0, (size_t)N * 4, stream);
    count_edges_kernel<<<(E + 255) / 256, 256, 0, stream>>>(coli, counts, E);
    dinv_kernel<<<(N + 255) / 256, 256, 0, stream>>>(counts, dinv, N);
    scan_kernel<<<1, 1024, 0, stream>>>(counts, offsets, cursor, N);
    fill_csr_kernel<<<(E + 255) / 256, 256, 0, stream>>>(rowi, coli, offsets, cursor, dinv, srcs, wnorm, E);

    const int gemm_grid = (N + 63) / 64;

    // ---- layer 1: hw = x @ W1 ; h = relu(agg(hw) + b1) ----
    gemm_kernel<128><<<gemm_grid, 256, 0, stream>>>(x, W1, bufA, N);
    agg_kernel<128, true><<<(N + 1) / 2, 256, 0, stream>>>(bufA, offsets, srcs, wnorm, dinv, b1, bufB, N);

    // ---- layer 2 ----
    gemm_kernel<128><<<gemm_grid, 256, 0, stream>>>(bufB, W2, bufA, N);
    agg_kernel<128, true><<<(N + 1) / 2, 256, 0, stream>>>(bufA, offsets, srcs, wnorm, dinv, b2, bufB, N);

    // ---- layer 3 (no relu), width 64, write d_out ----
    gemm_kernel<64><<<gemm_grid, 256, 0, stream>>>(bufB, W3, bufA, N);
    agg_kernel<64, false><<<(N + 3) / 4, 256, 0, stream>>>(bufA, offsets, srcs, wnorm, dinv, b3, out, N);
}

// Round 2
// 368.815 us; speedup vs baseline: 1.4511x; 1.4511x over previous
//
#include <hip/hip_runtime.h>
#include <hip/hip_bf16.h>

// GCN 3-layer: out = A_hat @ (A_hat @ relu(A_hat @ relu(X W1)+b1 ... ) )
// Strategy: per-call CSR build (atomic-free aggregation), f32 LDS-tiled GEMMs.
// R2: agg_kernel vectorized (float4/lane) + edge-loop unroll x4 for memory ILP.

#define THREADS 256

__global__ void count_edges_kernel(const int* __restrict__ col, int* __restrict__ counts, int E) {
    int e = blockIdx.x * blockDim.x + threadIdx.x;
    if (e < E) atomicAdd(&counts[col[e]], 1);
}

__global__ void dinv_kernel(const int* __restrict__ counts, float* __restrict__ dinv, int n) {
    int i = blockIdx.x * blockDim.x + threadIdx.x;
    if (i < n) {
        float deg = (float)(counts[i] + 1);  // +1 self loop
        dinv[i] = rsqrtf(deg);
    }
}

// Single-block exclusive scan over counts[n] -> offsets[n], offsets[n]=total. Also zeroes cursor.
__global__ void scan_kernel(const int* __restrict__ counts, int* __restrict__ offsets,
                            int* __restrict__ cursor, int n) {
    __shared__ int wsum[16];
    int tid = threadIdx.x;
    int lane = tid & 63, wid = tid >> 6;
    int running = 0;
    for (int base = 0; base < n; base += 1024) {
        int i = base + tid;
        int c = (i < n) ? counts[i] : 0;
        int v = c;
        #pragma unroll
        for (int d = 1; d < 64; d <<= 1) {
            int u = __shfl_up(v, d);
            if (lane >= d) v += u;
        }
        if (lane == 63) wsum[wid] = v;
        __syncthreads();
        if (tid < 16) {
            int s = wsum[tid];
            #pragma unroll
            for (int d = 1; d < 16; d <<= 1) {
                int u = __shfl_up(s, d);
                if (tid >= d) s += u;
            }
            wsum[tid] = s;
        }
        __syncthreads();
        int woff = (wid == 0) ? 0 : wsum[wid - 1];
        int incl = v + woff;
        if (i < n) {
            offsets[i] = running + incl - c;
            cursor[i] = 0;
        }
        running += wsum[15];
        __syncthreads();
    }
    if (tid == 0) offsets[n] = running;
}

__global__ void fill_csr_kernel(const int* __restrict__ row, const int* __restrict__ col,
                                const int* __restrict__ offsets, int* __restrict__ cursor,
                                const float* __restrict__ dinv,
                                int* __restrict__ srcs, float* __restrict__ wnorm, int E) {
    int e = blockIdx.x * blockDim.x + threadIdx.x;
    if (e < E) {
        int c = col[e];
        int r = row[e];
        int pos = offsets[c] + atomicAdd(&cursor[c], 1);
        srcs[pos] = r;
        wnorm[pos] = dinv[r] * dinv[c];
    }
}

// out[n, DO] = A[n,128] @ W[128, DO]   (no bias/act; those are fused into aggregation)
// 256 threads, 64 rows/block. Each thread: RPT rows x 8 cols register tile.
template <int DO>
__global__ __launch_bounds__(256) void gemm_kernel(const float* __restrict__ A,
                                                   const float* __restrict__ W,
                                                   float* __restrict__ out, int n) {
    constexpr int K = 128;
    constexpr int BR = 64;
    constexpr int LDA = K + 4;             // pad: bank-conflict-free A reads
    constexpr int COLTH = DO / 8;          // 16 (DO=128) or 8 (DO=64)
    constexpr int ROWTH = 256 / COLTH;     // 16 or 32
    constexpr int RPT = BR / ROWTH;        // 4 or 2

    __shared__ float Wl[K * DO];
    __shared__ float Al[BR * LDA];

    int tid = threadIdx.x;
    int rb = blockIdx.x * BR;

    // stage W (row-major [K][DO])
    for (int q = tid; q < K * DO / 4; q += 256) {
        ((float4*)Wl)[q] = ((const float4*)W)[q];
    }
    // stage A tile [BR][K] with padded stride
    for (int q = tid; q < BR * K / 4; q += 256) {
        int r = q >> 5;          // K/4 = 32 float4 per row
        int kq = q & 31;
        int row = rb + r;
        float4 v;
        if (row < n) v = ((const float4*)(A + (size_t)row * K))[kq];
        else { v.x = v.y = v.z = v.w = 0.f; }
        *(float4*)(Al + r * LDA + kq * 4) = v;
    }
    __syncthreads();

    int ct = tid % COLTH;   // cols ct*8 .. ct*8+7
    int rt = tid / COLTH;   // rows rt + ROWTH*i

    float4 acc0[RPT], acc1[RPT];
    #pragma unroll
    for (int i = 0; i < RPT; ++i) {
        acc0[i].x = acc0[i].y = acc0[i].z = acc0[i].w = 0.f;
        acc1[i].x = acc1[i].y = acc1[i].z = acc1[i].w = 0.f;
    }

    #pragma unroll 8
    for (int k = 0; k < K; ++k) {
        float4 w0 = *(const float4*)(Wl + k * DO + ct * 8);
        float4 w1 = *(const float4*)(Wl + k * DO + ct * 8 + 4);
        #pragma unroll
        for (int i = 0; i < RPT; ++i) {
            float a = Al[(rt + ROWTH * i) * LDA + k];
            acc0[i].x += a * w0.x; acc0[i].y += a * w0.y;
            acc0[i].z += a * w0.z; acc0[i].w += a * w0.w;
            acc1[i].x += a * w1.x; acc1[i].y += a * w1.y;
            acc1[i].z += a * w1.z; acc1[i].w += a * w1.w;
        }
    }

    #pragma unroll
    for (int i = 0; i < RPT; ++i) {
        int row = rb + rt + ROWTH * i;
        if (row < n) {
            *(float4*)(out + (size_t)row * DO + ct * 8) = acc0[i];
            *(float4*)(out + (size_t)row * DO + ct * 8 + 4) = acc1[i];
        }
    }
}

// Aggregation: out[d] = bias + hw[d]*dinv[d]^2 + sum_{e in CSR[d]} hw[srcs[e]] * wnorm[e]
// float4 per lane: TPD = DO/4 lanes per dest. Edge loop unrolled x4 => 4 independent
// dwordx4 gathers in flight per lane (latency hiding).
template <int DO, bool RELU>
__global__ __launch_bounds__(256) void agg_kernel(const float* __restrict__ hw,
                                                  const int* __restrict__ offsets,
                                                  const int* __restrict__ srcs,
                                                  const float* __restrict__ wnorm,
                                                  const float* __restrict__ dinv,
                                                  const float* __restrict__ bias,
                                                  float* __restrict__ out, int n) {
    constexpr int TPD = DO / 4;            // lanes per dest
    constexpr int DPB = 256 / TPD;         // dests per block
    int d = blockIdx.x * DPB + threadIdx.x / TPD;
    int j = threadIdx.x % TPD;             // float4 column index
    if (d >= n) return;

    const float4* hw4 = (const float4*)hw;
    int beg = offsets[d];
    int end = offsets[d + 1];
    float di = dinv[d];
    float sw = di * di;

    float4 b4 = ((const float4*)bias)[j];
    float4 self = hw4[(size_t)d * TPD + j];
    float4 acc;
    acc.x = b4.x + self.x * sw;
    acc.y = b4.y + self.y * sw;
    acc.z = b4.z + self.z * sw;
    acc.w = b4.w + self.w * sw;

    int e = beg;
    for (; e + 4 <= end; e += 4) {
        int s0 = srcs[e + 0], s1 = srcs[e + 1], s2 = srcs[e + 2], s3 = srcs[e + 3];
        float w0 = wnorm[e + 0], w1 = wnorm[e + 1], w2 = wnorm[e + 2], w3 = wnorm[e + 3];
        float4 v0 = hw4[(size_t)s0 * TPD + j];
        float4 v1 = hw4[(size_t)s1 * TPD + j];
        float4 v2 = hw4[(size_t)s2 * TPD + j];
        float4 v3 = hw4[(size_t)s3 * TPD + j];
        acc.x += v0.x * w0; acc.y += v0.y * w0; acc.z += v0.z * w0; acc.w += v0.w * w0;
        acc.x += v1.x * w1; acc.y += v1.y * w1; acc.z += v1.z * w1; acc.w += v1.w * w1;
        acc.x += v2.x * w2; acc.y += v2.y * w2; acc.z += v2.z * w2; acc.w += v2.w * w2;
        acc.x += v3.x * w3; acc.y += v3.y * w3; acc.z += v3.z * w3; acc.w += v3.w * w3;
    }
    for (; e < end; ++e) {
        int s = srcs[e];
        float w = wnorm[e];
        float4 v = hw4[(size_t)s * TPD + j];
        acc.x += v.x * w; acc.y += v.y * w; acc.z += v.z * w; acc.w += v.w * w;
    }

    if (RELU) {
        acc.x = fmaxf(acc.x, 0.f); acc.y = fmaxf(acc.y, 0.f);
        acc.z = fmaxf(acc.z, 0.f); acc.w = fmaxf(acc.w, 0.f);
    }
    ((float4*)out)[(size_t)d * TPD + j] = acc;
}

extern "C" void kernel_launch(void* const* d_in, const int* in_sizes, int n_in,
                              void* d_out, int out_size, void* d_ws, size_t ws_size,
                              hipStream_t stream) {
    const float* x  = (const float*)d_in[0];
    const float* W1 = (const float*)d_in[1];
    const float* b1 = (const float*)d_in[2];
    const float* W2 = (const float*)d_in[3];
    const float* b2 = (const float*)d_in[4];
    const float* W3 = (const float*)d_in[5];
    const float* b3 = (const float*)d_in[6];
    const int*   ei = (const int*)d_in[7];

    const int N = in_sizes[0] / 128;
    const int E = in_sizes[7] / 2;
    const int* rowi = ei;       // edge_index[0] = sources
    const int* coli = ei + E;   // edge_index[1] = targets

    float* out = (float*)d_out;

    // workspace carve-up (256B aligned)
    char* ws = (char*)d_ws;
    size_t off = 0;
    auto alloc = [&](size_t bytes) -> void* {
        void* p = ws + off;
        off = (off + bytes + 255) & ~(size_t)255;
        return p;
    };
    float* dinv    = (float*)alloc((size_t)N * 4);
    int*   counts  = (int*)  alloc((size_t)N * 4);
    int*   offsets = (int*)  alloc((size_t)(N + 1) * 4);
    int*   cursor  = (int*)  alloc((size_t)N * 4);
    int*   srcs    = (int*)  alloc((size_t)E * 4);
    float* wnorm   = (float*)alloc((size_t)E * 4);
    float* bufA    = (float*)alloc((size_t)N * 128 * 4);
    float* bufB    = (float*)alloc((size_t)N * 128 * 4);

    // ---- degree / norm / CSR ----
    hipMemsetAsync(counts, 0, (size_t)N * 4, stream);
    count_edges_kernel<<<(E + 255) / 256, 256, 0, stream>>>(coli, counts, E);
    dinv_kernel<<<(N + 255) / 256, 256, 0, stream>>>(counts, dinv, N);
    scan_kernel<<<1, 1024, 0, stream>>>(counts, offsets, cursor, N);
    fill_csr_kernel<<<(E + 255) / 256, 256, 0, stream>>>(rowi, coli, offsets, cursor, dinv, srcs, wnorm, E);

    const int gemm_grid = (N + 63) / 64;

    // ---- layer 1: hw = x @ W1 ; h = relu(agg(hw) + b1) ----
    gemm_kernel<128><<<gemm_grid, 256, 0, stream>>>(x, W1, bufA, N);
    agg_kernel<128, true><<<(N + 7) / 8, 256, 0, stream>>>(bufA, offsets, srcs, wnorm, dinv, b1, bufB, N);

    // ---- layer 2 ----
    gemm_kernel<128><<<gemm_grid, 256, 0, stream>>>(bufB, W2, bufA, N);
    agg_kernel<128, true><<<(N + 7) / 8, 256, 0, stream>>>(bufA, offsets, srcs, wnorm, dinv, b2, bufB, N);

    // ---- layer 3 (no relu), width 64, write d_out ----
    gemm_kernel<64><<<gemm_grid, 256, 0, stream>>>(bufB, W3, bufA, N);
    agg_kernel<64, false><<<(N + 15) / 16, 256, 0, stream>>>(bufA, offsets, srcs, wnorm, dinv, b3, out, N);
}

// Round 3
// 327.953 us; speedup vs baseline: 1.6320x; 1.1246x over previous
//
#include <hip/hip_runtime.h>
#include <hip/hip_bf16.h>

// GCN 3-layer: out = A_hat @ (A_hat @ relu(A_hat @ relu(X W1)+b1 ... ) )
// Strategy: per-call CSR build (atomic-free aggregation), f32 GEMMs.
// R2: agg_kernel vectorized (float4/lane) + edge-loop unroll x4 for memory ILP.
// R3: GEMM restructured — W-only LDS (64/32 KB), A streamed via wave-broadcast
//     global reads, 8x8 register tile, conflict-free W layout (16B lane stride).

#define THREADS 256

__global__ void count_edges_kernel(const int* __restrict__ col, int* __restrict__ counts, int E) {
    int e = blockIdx.x * blockDim.x + threadIdx.x;
    if (e < E) atomicAdd(&counts[col[e]], 1);
}

__global__ void dinv_kernel(const int* __restrict__ counts, float* __restrict__ dinv, int n) {
    int i = blockIdx.x * blockDim.x + threadIdx.x;
    if (i < n) {
        float deg = (float)(counts[i] + 1);  // +1 self loop
        dinv[i] = rsqrtf(deg);
    }
}

// Single-block exclusive scan over counts[n] -> offsets[n], offsets[n]=total. Also zeroes cursor.
__global__ void scan_kernel(const int* __restrict__ counts, int* __restrict__ offsets,
                            int* __restrict__ cursor, int n) {
    __shared__ int wsum[16];
    int tid = threadIdx.x;
    int lane = tid & 63, wid = tid >> 6;
    int running = 0;
    for (int base = 0; base < n; base += 1024) {
        int i = base + tid;
        int c = (i < n) ? counts[i] : 0;
        int v = c;
        #pragma unroll
        for (int d = 1; d < 64; d <<= 1) {
            int u = __shfl_up(v, d);
            if (lane >= d) v += u;
        }
        if (lane == 63) wsum[wid] = v;
        __syncthreads();
        if (tid < 16) {
            int s = wsum[tid];
            #pragma unroll
            for (int d = 1; d < 16; d <<= 1) {
                int u = __shfl_up(s, d);
                if (tid >= d) s += u;
            }
            wsum[tid] = s;
        }
        __syncthreads();
        int woff = (wid == 0) ? 0 : wsum[wid - 1];
        int incl = v + woff;
        if (i < n) {
            offsets[i] = running + incl - c;
            cursor[i] = 0;
        }
        running += wsum[15];
        __syncthreads();
    }
    if (tid == 0) offsets[n] = running;
}

__global__ void fill_csr_kernel(const int* __restrict__ row, const int* __restrict__ col,
                                const int* __restrict__ offsets, int* __restrict__ cursor,
                                const float* __restrict__ dinv,
                                int* __restrict__ srcs, float* __restrict__ wnorm, int E) {
    int e = blockIdx.x * blockDim.x + threadIdx.x;
    if (e < E) {
        int c = col[e];
        int r = row[e];
        int pos = offsets[c] + atomicAdd(&cursor[c], 1);
        srcs[pos] = r;
        wnorm[pos] = dinv[r] * dinv[c];
    }
}

// out[n, DO] = A[n,128] @ W[128, DO]
// 256 threads. Thread (rt, ct) owns 8 contiguous rows (rt*8..rt*8+7) and 8 cols
// as two 4-col chunks: [ct*4 .. ct*4+3] and [DO/2 + ct*4 ..]. W staged in LDS
// (row-major [K][DO]); per-k lane reads are 16B-strided -> 2-way bank alias (free).
// A read directly from global: all ct-threads of an rt-group read the SAME address
// (wave broadcast) so A streams once per block. 64 f32 acc/thread, deep FMA ILP.
template <int DO>
__global__ __launch_bounds__(256, 2) void gemm_kernel(const float* __restrict__ A,
                                                      const float* __restrict__ W,
                                                      float* __restrict__ out, int n) {
    constexpr int K = 128;
    constexpr int COLTH = DO / 8;          // 16 (DO=128) or 8 (DO=64)
    constexpr int ROWTH = 256 / COLTH;     // 16 or 32
    constexpr int R = 8;                   // rows per thread
    constexpr int BR = ROWTH * R;          // 128 or 256 rows per block
    constexpr int HALF = DO / 2;

    __shared__ float Wl[K * DO];           // 64 KB (DO=128) / 32 KB (DO=64)

    int tid = threadIdx.x;
    // stage W (row-major [K][DO]), float4 coalesced
    #pragma unroll
    for (int q = tid; q < K * DO / 4; q += 256) {
        ((float4*)Wl)[q] = ((const float4*)W)[q];
    }
    __syncthreads();

    int ct = tid % COLTH;
    int rt = tid / COLTH;
    int rb = blockIdx.x * BR + rt * R;     // first of this thread's 8 rows

    const float4* A4 = (const float4*)A;

    int rowc[R];
    #pragma unroll
    for (int i = 0; i < R; ++i) {
        int row = rb + i;
        rowc[i] = (row < n) ? row : (n - 1);   // clamp loads; stores guarded below
    }

    float4 acc[R][2];
    #pragma unroll
    for (int i = 0; i < R; ++i) {
        acc[i][0].x = acc[i][0].y = acc[i][0].z = acc[i][0].w = 0.f;
        acc[i][1].x = acc[i][1].y = acc[i][1].z = acc[i][1].w = 0.f;
    }

    #pragma unroll 2
    for (int k4 = 0; k4 < K / 4; ++k4) {
        float4 areg[R];
        #pragma unroll
        for (int i = 0; i < R; ++i) {
            areg[i] = A4[(size_t)rowc[i] * (K / 4) + k4];
        }
        #pragma unroll
        for (int q = 0; q < 4; ++q) {
            int k = k4 * 4 + q;
            float4 w0 = *(const float4*)(Wl + k * DO + ct * 4);
            float4 w1 = *(const float4*)(Wl + k * DO + HALF + ct * 4);
            #pragma unroll
            for (int i = 0; i < R; ++i) {
                float a = (q == 0) ? areg[i].x : (q == 1) ? areg[i].y
                        : (q == 2) ? areg[i].z : areg[i].w;
                acc[i][0].x += a * w0.x; acc[i][0].y += a * w0.y;
                acc[i][0].z += a * w0.z; acc[i][0].w += a * w0.w;
                acc[i][1].x += a * w1.x; acc[i][1].y += a * w1.y;
                acc[i][1].z += a * w1.z; acc[i][1].w += a * w1.w;
            }
        }
    }

    #pragma unroll
    for (int i = 0; i < R; ++i) {
        int row = rb + i;
        if (row < n) {
            *(float4*)(out + (size_t)row * DO + ct * 4) = acc[i][0];
            *(float4*)(out + (size_t)row * DO + HALF + ct * 4) = acc[i][1];
        }
    }
}

// Aggregation: out[d] = bias + hw[d]*dinv[d]^2 + sum_{e in CSR[d]} hw[srcs[e]] * wnorm[e]
// float4 per lane: TPD = DO/4 lanes per dest. Edge loop unrolled x4 => 4 independent
// dwordx4 gathers in flight per lane (latency hiding).
template <int DO, bool RELU>
__global__ __launch_bounds__(256) void agg_kernel(const float* __restrict__ hw,
                                                  const int* __restrict__ offsets,
                                                  const int* __restrict__ srcs,
                                                  const float* __restrict__ wnorm,
                                                  const float* __restrict__ dinv,
                                                  const float* __restrict__ bias,
                                                  float* __restrict__ out, int n) {
    constexpr int TPD = DO / 4;            // lanes per dest
    constexpr int DPB = 256 / TPD;         // dests per block
    int d = blockIdx.x * DPB + threadIdx.x / TPD;
    int j = threadIdx.x % TPD;             // float4 column index
    if (d >= n) return;

    const float4* hw4 = (const float4*)hw;
    int beg = offsets[d];
    int end = offsets[d + 1];
    float di = dinv[d];
    float sw = di * di;

    float4 b4 = ((const float4*)bias)[j];
    float4 self = hw4[(size_t)d * TPD + j];
    float4 acc;
    acc.x = b4.x + self.x * sw;
    acc.y = b4.y + self.y * sw;
    acc.z = b4.z + self.z * sw;
    acc.w = b4.w + self.w * sw;

    int e = beg;
    for (; e + 4 <= end; e += 4) {
        int s0 = srcs[e + 0], s1 = srcs[e + 1], s2 = srcs[e + 2], s3 = srcs[e + 3];
        float w0 = wnorm[e + 0], w1 = wnorm[e + 1], w2 = wnorm[e + 2], w3 = wnorm[e + 3];
        float4 v0 = hw4[(size_t)s0 * TPD + j];
        float4 v1 = hw4[(size_t)s1 * TPD + j];
        float4 v2 = hw4[(size_t)s2 * TPD + j];
        float4 v3 = hw4[(size_t)s3 * TPD + j];
        acc.x += v0.x * w0; acc.y += v0.y * w0; acc.z += v0.z * w0; acc.w += v0.w * w0;
        acc.x += v1.x * w1; acc.y += v1.y * w1; acc.z += v1.z * w1; acc.w += v1.w * w1;
        acc.x += v2.x * w2; acc.y += v2.y * w2; acc.z += v2.z * w2; acc.w += v2.w * w2;
        acc.x += v3.x * w3; acc.y += v3.y * w3; acc.z += v3.z * w3; acc.w += v3.w * w3;
    }
    for (; e < end; ++e) {
        int s = srcs[e];
        float w = wnorm[e];
        float4 v = hw4[(size_t)s * TPD + j];
        acc.x += v.x * w; acc.y += v.y * w; acc.z += v.z * w; acc.w += v.w * w;
    }

    if (RELU) {
        acc.x = fmaxf(acc.x, 0.f); acc.y = fmaxf(acc.y, 0.f);
        acc.z = fmaxf(acc.z, 0.f); acc.w = fmaxf(acc.w, 0.f);
    }
    ((float4*)out)[(size_t)d * TPD + j] = acc;
}

extern "C" void kernel_launch(void* const* d_in, const int* in_sizes, int n_in,
                              void* d_out, int out_size, void* d_ws, size_t ws_size,
                              hipStream_t stream) {
    const float* x  = (const float*)d_in[0];
    const float* W1 = (const float*)d_in[1];
    const float* b1 = (const float*)d_in[2];
    const float* W2 = (const float*)d_in[3];
    const float* b2 = (const float*)d_in[4];
    const float* W3 = (const float*)d_in[5];
    const float* b3 = (const float*)d_in[6];
    const int*   ei = (const int*)d_in[7];

    const int N = in_sizes[0] / 128;
    const int E = in_sizes[7] / 2;
    const int* rowi = ei;       // edge_index[0] = sources
    const int* coli = ei + E;   // edge_index[1] = targets

    float* out = (float*)d_out;

    // workspace carve-up (256B aligned)
    char* ws = (char*)d_ws;
    size_t off = 0;
    auto alloc = [&](size_t bytes) -> void* {
        void* p = ws + off;
        off = (off + bytes + 255) & ~(size_t)255;
        return p;
    };
    float* dinv    = (float*)alloc((size_t)N * 4);
    int*   counts  = (int*)  alloc((size_t)N * 4);
    int*   offsets = (int*)  alloc((size_t)(N + 1) * 4);
    int*   cursor  = (int*)  alloc((size_t)N * 4);
    int*   srcs    = (int*)  alloc((size_t)E * 4);
    float* wnorm   = (float*)alloc((size_t)E * 4);
    float* bufA    = (float*)alloc((size_t)N * 128 * 4);
    float* bufB    = (float*)alloc((size_t)N * 128 * 4);

    // ---- degree / norm / CSR ----
    hipMemsetAsync(counts, 0, (size_t)N * 4, stream);
    count_edges_kernel<<<(E + 255) / 256, 256, 0, stream>>>(coli, counts, E);
    dinv_kernel<<<(N + 255) / 256, 256, 0, stream>>>(counts, dinv, N);
    scan_kernel<<<1, 1024, 0, stream>>>(counts, offsets, cursor, N);
    fill_csr_kernel<<<(E + 255) / 256, 256, 0, stream>>>(rowi, coli, offsets, cursor, dinv, srcs, wnorm, E);

    // ---- layer 1: hw = x @ W1 ; h = relu(agg(hw) + b1) ----
    gemm_kernel<128><<<(N + 127) / 128, 256, 0, stream>>>(x, W1, bufA, N);
    agg_kernel<128, true><<<(N + 7) / 8, 256, 0, stream>>>(bufA, offsets, srcs, wnorm, dinv, b1, bufB, N);

    // ---- layer 2 ----
    gemm_kernel<128><<<(N + 127) / 128, 256, 0, stream>>>(bufB, W2, bufA, N);
    agg_kernel<128, true><<<(N + 7) / 8, 256, 0, stream>>>(bufA, offsets, srcs, wnorm, dinv, b2, bufB, N);

    // ---- layer 3 (no relu), width 64, write d_out ----
    gemm_kernel<64><<<(N + 255) / 256, 256, 0, stream>>>(bufB, W3, bufA, N);
    agg_kernel<64, false><<<(N + 15) / 16, 256, 0, stream>>>(bufA, offsets, srcs, wnorm, dinv, b3, out, N);
}

// Round 4
// 276.131 us; speedup vs baseline: 1.9382x; 1.1877x over previous
//
#include <hip/hip_runtime.h>
#include <hip/hip_bf16.h>
#include <hip/hip_fp16.h>

// GCN 3-layer: out = A_hat @ (A_hat @ relu(A_hat @ relu(X W1)+b1 ... ) )
// R2: agg vectorized + unrolled. R3: GEMM W-only-LDS, 8x8 reg tile.
// R4: hw (GEMM output / gather table) stored as fp16 -> halves gather+write
//     traffic; (src,wnorm) packed into one 8B record -> halves fill_csr scatter
//     line traffic; agg unroll x8.

__device__ inline float4 h4_to_f4(float2 raw) {
    __half2 lo = *reinterpret_cast<__half2*>(&raw.x);
    __half2 hi = *reinterpret_cast<__half2*>(&raw.y);
    float2 a = __half22float2(lo);
    float2 b = __half22float2(hi);
    return make_float4(a.x, a.y, b.x, b.y);
}

__device__ inline float2 f4_to_h4(float4 v) {
    __half2 lo = __floats2half2_rn(v.x, v.y);
    __half2 hi = __floats2half2_rn(v.z, v.w);
    float2 r;
    r.x = *reinterpret_cast<float*>(&lo);
    r.y = *reinterpret_cast<float*>(&hi);
    return r;
}

__global__ void count_edges_kernel(const int* __restrict__ col, int* __restrict__ counts, int E) {
    int e = blockIdx.x * blockDim.x + threadIdx.x;
    if (e < E) atomicAdd(&counts[col[e]], 1);
}

__global__ void dinv_kernel(const int* __restrict__ counts, float* __restrict__ dinv, int n) {
    int i = blockIdx.x * blockDim.x + threadIdx.x;
    if (i < n) {
        float deg = (float)(counts[i] + 1);  // +1 self loop
        dinv[i] = rsqrtf(deg);
    }
}

// Single-block exclusive scan over counts[n] -> offsets[n], offsets[n]=total. Also zeroes cursor.
__global__ void scan_kernel(const int* __restrict__ counts, int* __restrict__ offsets,
                            int* __restrict__ cursor, int n) {
    __shared__ int wsum[16];
    int tid = threadIdx.x;
    int lane = tid & 63, wid = tid >> 6;
    int running = 0;
    for (int base = 0; base < n; base += 1024) {
        int i = base + tid;
        int c = (i < n) ? counts[i] : 0;
        int v = c;
        #pragma unroll
        for (int d = 1; d < 64; d <<= 1) {
            int u = __shfl_up(v, d);
            if (lane >= d) v += u;
        }
        if (lane == 63) wsum[wid] = v;
        __syncthreads();
        if (tid < 16) {
            int s = wsum[tid];
            #pragma unroll
            for (int d = 1; d < 16; d <<= 1) {
                int u = __shfl_up(s, d);
                if (tid >= d) s += u;
            }
            wsum[tid] = s;
        }
        __syncthreads();
        int woff = (wid == 0) ? 0 : wsum[wid - 1];
        int incl = v + woff;
        if (i < n) {
            offsets[i] = running + incl - c;
            cursor[i] = 0;
        }
        running += wsum[15];
        __syncthreads();
    }
    if (tid == 0) offsets[n] = running;
}

// One 8B scattered store per edge: (src, bitcast(wnorm)).
__global__ void fill_csr_kernel(const int* __restrict__ row, const int* __restrict__ col,
                                const int* __restrict__ offsets, int* __restrict__ cursor,
                                const float* __restrict__ dinv,
                                int2* __restrict__ edges, int E) {
    int e = blockIdx.x * blockDim.x + threadIdx.x;
    if (e < E) {
        int c = col[e];
        int r = row[e];
        int pos = offsets[c] + atomicAdd(&cursor[c], 1);
        edges[pos] = make_int2(r, __float_as_int(dinv[r] * dinv[c]));
    }
}

// out16[n, DO] (fp16) = A[n,128] @ W[128, DO]; f32 accumulation, f16 store.
// Thread (rt, ct): 8 contiguous rows x 8 cols (two 4-col chunks DO/2 apart).
// W in LDS (16B lane stride -> conflict-free); A wave-broadcast from global.
template <int DO>
__global__ __launch_bounds__(256, 2) void gemm_kernel(const float* __restrict__ A,
                                                      const float* __restrict__ W,
                                                      __half* __restrict__ out, int n) {
    constexpr int K = 128;
    constexpr int COLTH = DO / 8;          // 16 (DO=128) or 8 (DO=64)
    constexpr int ROWTH = 256 / COLTH;     // 16 or 32
    constexpr int R = 8;                   // rows per thread
    constexpr int BR = ROWTH * R;          // 128 or 256 rows per block
    constexpr int HALF = DO / 2;

    __shared__ float Wl[K * DO];           // 64 KB (DO=128) / 32 KB (DO=64)

    int tid = threadIdx.x;
    #pragma unroll
    for (int q = tid; q < K * DO / 4; q += 256) {
        ((float4*)Wl)[q] = ((const float4*)W)[q];
    }
    __syncthreads();

    int ct = tid % COLTH;
    int rt = tid / COLTH;
    int rb = blockIdx.x * BR + rt * R;

    const float4* A4 = (const float4*)A;

    int rowc[R];
    #pragma unroll
    for (int i = 0; i < R; ++i) {
        int row = rb + i;
        rowc[i] = (row < n) ? row : (n - 1);
    }

    float4 acc[R][2];
    #pragma unroll
    for (int i = 0; i < R; ++i) {
        acc[i][0].x = acc[i][0].y = acc[i][0].z = acc[i][0].w = 0.f;
        acc[i][1].x = acc[i][1].y = acc[i][1].z = acc[i][1].w = 0.f;
    }

    #pragma unroll 2
    for (int k4 = 0; k4 < K / 4; ++k4) {
        float4 areg[R];
        #pragma unroll
        for (int i = 0; i < R; ++i) {
            areg[i] = A4[(size_t)rowc[i] * (K / 4) + k4];
        }
        #pragma unroll
        for (int q = 0; q < 4; ++q) {
            int k = k4 * 4 + q;
            float4 w0 = *(const float4*)(Wl + k * DO + ct * 4);
            float4 w1 = *(const float4*)(Wl + k * DO + HALF + ct * 4);
            #pragma unroll
            for (int i = 0; i < R; ++i) {
                float a = (q == 0) ? areg[i].x : (q == 1) ? areg[i].y
                        : (q == 2) ? areg[i].z : areg[i].w;
                acc[i][0].x += a * w0.x; acc[i][0].y += a * w0.y;
                acc[i][0].z += a * w0.z; acc[i][0].w += a * w0.w;
                acc[i][1].x += a * w1.x; acc[i][1].y += a * w1.y;
                acc[i][1].z += a * w1.z; acc[i][1].w += a * w1.w;
            }
        }
    }

    #pragma unroll
    for (int i = 0; i < R; ++i) {
        int row = rb + i;
        if (row < n) {
            *(float2*)(out + (size_t)row * DO + ct * 4) = f4_to_h4(acc[i][0]);
            *(float2*)(out + (size_t)row * DO + HALF + ct * 4) = f4_to_h4(acc[i][1]);
        }
    }
}

// out[d] = bias + hw[d]*dinv[d]^2 + sum_e hw16[src(e)] * wnorm(e)   (f32 acc)
// TPD = DO/4 lanes/dest, each lane covers 4 cols (8B f16 gather). Unroll x8.
template <int DO, bool RELU>
__global__ __launch_bounds__(256) void agg_kernel(const __half* __restrict__ hw,
                                                  const int* __restrict__ offsets,
                                                  const int2* __restrict__ edges,
                                                  const float* __restrict__ dinv,
                                                  const float* __restrict__ bias,
                                                  float* __restrict__ out, int n) {
    constexpr int TPD = DO / 4;            // lanes per dest
    constexpr int DPB = 256 / TPD;         // dests per block
    int d = blockIdx.x * DPB + threadIdx.x / TPD;
    int j = threadIdx.x % TPD;             // 4-col chunk index
    if (d >= n) return;

    const float2* hw2 = (const float2*)hw; // 4 halves per unit
    int beg = offsets[d];
    int end = offsets[d + 1];
    float di = dinv[d];
    float sw = di * di;

    float4 b4 = ((const float4*)bias)[j];
    float4 self = h4_to_f4(hw2[(size_t)d * TPD + j]);
    float4 acc;
    acc.x = b4.x + self.x * sw;
    acc.y = b4.y + self.y * sw;
    acc.z = b4.z + self.z * sw;
    acc.w = b4.w + self.w * sw;

    int e = beg;
    #define EDGE_FMA(EE) do {                                            \
        int2 er = edges[EE];                                             \
        float w = __int_as_float(er.y);                                  \
        float4 v = h4_to_f4(hw2[(size_t)er.x * TPD + j]);                \
        acc.x += v.x * w; acc.y += v.y * w;                              \
        acc.z += v.z * w; acc.w += v.w * w;                              \
    } while (0)

    for (; e + 8 <= end; e += 8) {
        int2 r0 = edges[e + 0], r1 = edges[e + 1], r2 = edges[e + 2], r3 = edges[e + 3];
        int2 r4 = edges[e + 4], r5 = edges[e + 5], r6 = edges[e + 6], r7 = edges[e + 7];
        float4 v0 = h4_to_f4(hw2[(size_t)r0.x * TPD + j]);
        float4 v1 = h4_to_f4(hw2[(size_t)r1.x * TPD + j]);
        float4 v2 = h4_to_f4(hw2[(size_t)r2.x * TPD + j]);
        float4 v3 = h4_to_f4(hw2[(size_t)r3.x * TPD + j]);
        float4 v4 = h4_to_f4(hw2[(size_t)r4.x * TPD + j]);
        float4 v5 = h4_to_f4(hw2[(size_t)r5.x * TPD + j]);
        float4 v6 = h4_to_f4(hw2[(size_t)r6.x * TPD + j]);
        float4 v7 = h4_to_f4(hw2[(size_t)r7.x * TPD + j]);
        float w0 = __int_as_float(r0.y), w1 = __int_as_float(r1.y);
        float w2 = __int_as_float(r2.y), w3 = __int_as_float(r3.y);
        float w4 = __int_as_float(r4.y), w5 = __int_as_float(r5.y);
        float w6 = __int_as_float(r6.y), w7 = __int_as_float(r7.y);
        acc.x += v0.x * w0; acc.y += v0.y * w0; acc.z += v0.z * w0; acc.w += v0.w * w0;
        acc.x += v1.x * w1; acc.y += v1.y * w1; acc.z += v1.z * w1; acc.w += v1.w * w1;
        acc.x += v2.x * w2; acc.y += v2.y * w2; acc.z += v2.z * w2; acc.w += v2.w * w2;
        acc.x += v3.x * w3; acc.y += v3.y * w3; acc.z += v3.z * w3; acc.w += v3.w * w3;
        acc.x += v4.x * w4; acc.y += v4.y * w4; acc.z += v4.z * w4; acc.w += v4.w * w4;
        acc.x += v5.x * w5; acc.y += v5.y * w5; acc.z += v5.z * w5; acc.w += v5.w * w5;
        acc.x += v6.x * w6; acc.y += v6.y * w6; acc.z += v6.z * w6; acc.w += v6.w * w6;
        acc.x += v7.x * w7; acc.y += v7.y * w7; acc.z += v7.z * w7; acc.w += v7.w * w7;
    }
    for (; e + 4 <= end; e += 4) {
        int2 r0 = edges[e + 0], r1 = edges[e + 1], r2 = edges[e + 2], r3 = edges[e + 3];
        float4 v0 = h4_to_f4(hw2[(size_t)r0.x * TPD + j]);
        float4 v1 = h4_to_f4(hw2[(size_t)r1.x * TPD + j]);
        float4 v2 = h4_to_f4(hw2[(size_t)r2.x * TPD + j]);
        float4 v3 = h4_to_f4(hw2[(size_t)r3.x * TPD + j]);
        float w0 = __int_as_float(r0.y), w1 = __int_as_float(r1.y);
        float w2 = __int_as_float(r2.y), w3 = __int_as_float(r3.y);
        acc.x += v0.x * w0; acc.y += v0.y * w0; acc.z += v0.z * w0; acc.w += v0.w * w0;
        acc.x += v1.x * w1; acc.y += v1.y * w1; acc.z += v1.z * w1; acc.w += v1.w * w1;
        acc.x += v2.x * w2; acc.y += v2.y * w2; acc.z += v2.z * w2; acc.w += v2.w * w2;
        acc.x += v3.x * w3; acc.y += v3.y * w3; acc.z += v3.z * w3; acc.w += v3.w * w3;
    }
    for (; e < end; ++e) EDGE_FMA(e);
    #undef EDGE_FMA

    if (RELU) {
        acc.x = fmaxf(acc.x, 0.f); acc.y = fmaxf(acc.y, 0.f);
        acc.z = fmaxf(acc.z, 0.f); acc.w = fmaxf(acc.w, 0.f);
    }
    ((float4*)out)[(size_t)d * TPD + j] = acc;
}

extern "C" void kernel_launch(void* const* d_in, const int* in_sizes, int n_in,
                              void* d_out, int out_size, void* d_ws, size_t ws_size,
                              hipStream_t stream) {
    const float* x  = (const float*)d_in[0];
    const float* W1 = (const float*)d_in[1];
    const float* b1 = (const float*)d_in[2];
    const float* W2 = (const float*)d_in[3];
    const float* b2 = (const float*)d_in[4];
    const float* W3 = (const float*)d_in[5];
    const float* b3 = (const float*)d_in[6];
    const int*   ei = (const int*)d_in[7];

    const int N = in_sizes[0] / 128;
    const int E = in_sizes[7] / 2;
    const int* rowi = ei;       // edge_index[0] = sources
    const int* coli = ei + E;   // edge_index[1] = targets

    float* out = (float*)d_out;

    // workspace carve-up (256B aligned)
    char* ws = (char*)d_ws;
    size_t off = 0;
    auto alloc = [&](size_t bytes) -> void* {
        void* p = ws + off;
        off = (off + bytes + 255) & ~(size_t)255;
        return p;
    };
    float* dinv    = (float*)alloc((size_t)N * 4);
    int*   counts  = (int*)  alloc((size_t)N * 4);
    int*   offsets = (int*)  alloc((size_t)(N + 1) * 4);
    int*   cursor  = (int*)  alloc((size_t)N * 4);
    int2*  edges   = (int2*) alloc((size_t)E * 8);
    __half* hw16   = (__half*)alloc((size_t)N * 128 * 2);
    float* hbuf    = (float*)alloc((size_t)N * 128 * 4);

    // ---- degree / norm / CSR ----
    hipMemsetAsync(counts, 0, (size_t)N * 4, stream);
    count_edges_kernel<<<(E + 255) / 256, 256, 0, stream>>>(coli, counts, E);
    dinv_kernel<<<(N + 255) / 256, 256, 0, stream>>>(counts, dinv, N);
    scan_kernel<<<1, 1024, 0, stream>>>(counts, offsets, cursor, N);
    fill_csr_kernel<<<(E + 255) / 256, 256, 0, stream>>>(rowi, coli, offsets, cursor, dinv, edges, E);

    // ---- layer 1: hw16 = f16(x @ W1); h = relu(agg(hw16) + b1) ----
    gemm_kernel<128><<<(N + 127) / 128, 256, 0, stream>>>(x, W1, hw16, N);
    agg_kernel<128, true><<<(N + 7) / 8, 256, 0, stream>>>(hw16, offsets, edges, dinv, b1, hbuf, N);

    // ---- layer 2 ----
    gemm_kernel<128><<<(N + 127) / 128, 256, 0, stream>>>(hbuf, W2, hw16, N);
    agg_kernel<128, true><<<(N + 7) / 8, 256, 0, stream>>>(hw16, offsets, edges, dinv, b2, hbuf, N);

    // ---- layer 3 (no relu), width 64, write d_out ----
    gemm_kernel<64><<<(N + 255) / 256, 256, 0, stream>>>(hbuf, W3, hw16, N);
    agg_kernel<64, false><<<(N + 15) / 16, 256, 0, stream>>>(hw16, offsets, edges, dinv, b3, out, N);
}

// Round 5
// 233.489 us; speedup vs baseline: 2.2922x; 1.1826x over previous
//
#include <hip/hip_runtime.h>
#include <hip/hip_bf16.h>
#include <hip/hip_fp16.h>

// GCN 3-layer: out = A_hat @ (A_hat @ relu(A_hat @ relu(X W1)+b1 ... ) )
// R2: agg vectorized + unrolled. R3: GEMM W-only-LDS, 8x8 reg tile.
// R4: fp16 gather table + packed 8B edge records.
// R5: single-block scan (46.5us, 1 CU) -> 3-stage device-wide scan (~8us);
//     dinv fused into write_offsets.

__device__ inline float4 h4_to_f4(float2 raw) {
    __half2 lo = *reinterpret_cast<__half2*>(&raw.x);
    __half2 hi = *reinterpret_cast<__half2*>(&raw.y);
    float2 a = __half22float2(lo);
    float2 b = __half22float2(hi);
    return make_float4(a.x, a.y, b.x, b.y);
}

__device__ inline float2 f4_to_h4(float4 v) {
    __half2 lo = __floats2half2_rn(v.x, v.y);
    __half2 hi = __floats2half2_rn(v.z, v.w);
    float2 r;
    r.x = *reinterpret_cast<float*>(&lo);
    r.y = *reinterpret_cast<float*>(&hi);
    return r;
}

__global__ void count_edges_kernel(const int* __restrict__ col, int* __restrict__ counts, int E) {
    int e = blockIdx.x * blockDim.x + threadIdx.x;
    if (e < E) atomicAdd(&counts[col[e]], 1);
}

// Stage 1: per-block (256 elements) sum of counts.
__global__ __launch_bounds__(256) void block_sum_kernel(const int* __restrict__ counts,
                                                        int* __restrict__ blocksum, int n) {
    int i = blockIdx.x * 256 + threadIdx.x;
    int v = (i < n) ? counts[i] : 0;
    #pragma unroll
    for (int d = 1; d < 64; d <<= 1) v += __shfl_xor(v, d);
    __shared__ int ws[4];
    if ((threadIdx.x & 63) == 0) ws[threadIdx.x >> 6] = v;
    __syncthreads();
    if (threadIdx.x == 0) blocksum[blockIdx.x] = ws[0] + ws[1] + ws[2] + ws[3];
}

// Stage 2: one block scans nb (<=256) block sums -> exclusive blockoff; offsets[n]=total.
__global__ __launch_bounds__(256) void scan_sums_kernel(const int* __restrict__ blocksum,
                                                        int* __restrict__ blockoff,
                                                        int* __restrict__ offsets, int nb, int n) {
    int tid = threadIdx.x;
    int lane = tid & 63, wid = tid >> 6;
    int orig = (tid < nb) ? blocksum[tid] : 0;
    int v = orig;
    #pragma unroll
    for (int d = 1; d < 64; d <<= 1) {
        int u = __shfl_up(v, d);
        if (lane >= d) v += u;
    }
    __shared__ int ws[4];
    if (lane == 63) ws[wid] = v;
    __syncthreads();
    int add = 0;
    for (int w = 0; w < wid; ++w) add += ws[w];
    v += add;                                  // inclusive
    if (tid < nb) blockoff[tid] = v - orig;    // exclusive
    if (tid == 255) offsets[n] = v;            // tail zeros -> total
}

// Stage 3: intra-chunk exclusive scan + blockoff -> offsets; zero cursor; fused dinv.
__global__ __launch_bounds__(256) void write_offsets_kernel(const int* __restrict__ counts,
                                                            const int* __restrict__ blockoff,
                                                            int* __restrict__ offsets,
                                                            int* __restrict__ cursor,
                                                            float* __restrict__ dinv, int n) {
    int tid = threadIdx.x;
    int i = blockIdx.x * 256 + tid;
    int lane = tid & 63, wid = tid >> 6;
    int c = (i < n) ? counts[i] : 0;
    int v = c;
    #pragma unroll
    for (int d = 1; d < 64; d <<= 1) {
        int u = __shfl_up(v, d);
        if (lane >= d) v += u;
    }
    __shared__ int ws[4];
    if (lane == 63) ws[wid] = v;
    __syncthreads();
    int add = 0;
    for (int w = 0; w < wid; ++w) add += ws[w];
    int incl = v + add;
    if (i < n) {
        offsets[i] = blockoff[blockIdx.x] + incl - c;
        cursor[i] = 0;
        dinv[i] = rsqrtf((float)(c + 1));      // +1 self loop
    }
}

// One 8B scattered store per edge: (src, bitcast(wnorm)).
__global__ void fill_csr_kernel(const int* __restrict__ row, const int* __restrict__ col,
                                const int* __restrict__ offsets, int* __restrict__ cursor,
                                const float* __restrict__ dinv,
                                int2* __restrict__ edges, int E) {
    int e = blockIdx.x * blockDim.x + threadIdx.x;
    if (e < E) {
        int c = col[e];
        int r = row[e];
        int pos = offsets[c] + atomicAdd(&cursor[c], 1);
        edges[pos] = make_int2(r, __float_as_int(dinv[r] * dinv[c]));
    }
}

// out16[n, DO] (fp16) = A[n,128] @ W[128, DO]; f32 accumulation, f16 store.
// Thread (rt, ct): 8 contiguous rows x 8 cols (two 4-col chunks DO/2 apart).
// W in LDS (16B lane stride -> conflict-free); A wave-broadcast from global.
template <int DO>
__global__ __launch_bounds__(256, 2) void gemm_kernel(const float* __restrict__ A,
                                                      const float* __restrict__ W,
                                                      __half* __restrict__ out, int n) {
    constexpr int K = 128;
    constexpr int COLTH = DO / 8;          // 16 (DO=128) or 8 (DO=64)
    constexpr int ROWTH = 256 / COLTH;     // 16 or 32
    constexpr int R = 8;                   // rows per thread
    constexpr int BR = ROWTH * R;          // 128 or 256 rows per block
    constexpr int HALF = DO / 2;

    __shared__ float Wl[K * DO];           // 64 KB (DO=128) / 32 KB (DO=64)

    int tid = threadIdx.x;
    #pragma unroll
    for (int q = tid; q < K * DO / 4; q += 256) {
        ((float4*)Wl)[q] = ((const float4*)W)[q];
    }
    __syncthreads();

    int ct = tid % COLTH;
    int rt = tid / COLTH;
    int rb = blockIdx.x * BR + rt * R;

    const float4* A4 = (const float4*)A;

    int rowc[R];
    #pragma unroll
    for (int i = 0; i < R; ++i) {
        int row = rb + i;
        rowc[i] = (row < n) ? row : (n - 1);
    }

    float4 acc[R][2];
    #pragma unroll
    for (int i = 0; i < R; ++i) {
        acc[i][0].x = acc[i][0].y = acc[i][0].z = acc[i][0].w = 0.f;
        acc[i][1].x = acc[i][1].y = acc[i][1].z = acc[i][1].w = 0.f;
    }

    #pragma unroll 2
    for (int k4 = 0; k4 < K / 4; ++k4) {
        float4 areg[R];
        #pragma unroll
        for (int i = 0; i < R; ++i) {
            areg[i] = A4[(size_t)rowc[i] * (K / 4) + k4];
        }
        #pragma unroll
        for (int q = 0; q < 4; ++q) {
            int k = k4 * 4 + q;
            float4 w0 = *(const float4*)(Wl + k * DO + ct * 4);
            float4 w1 = *(const float4*)(Wl + k * DO + HALF + ct * 4);
            #pragma unroll
            for (int i = 0; i < R; ++i) {
                float a = (q == 0) ? areg[i].x : (q == 1) ? areg[i].y
                        : (q == 2) ? areg[i].z : areg[i].w;
                acc[i][0].x += a * w0.x; acc[i][0].y += a * w0.y;
                acc[i][0].z += a * w0.z; acc[i][0].w += a * w0.w;
                acc[i][1].x += a * w1.x; acc[i][1].y += a * w1.y;
                acc[i][1].z += a * w1.z; acc[i][1].w += a * w1.w;
            }
        }
    }

    #pragma unroll
    for (int i = 0; i < R; ++i) {
        int row = rb + i;
        if (row < n) {
            *(float2*)(out + (size_t)row * DO + ct * 4) = f4_to_h4(acc[i][0]);
            *(float2*)(out + (size_t)row * DO + HALF + ct * 4) = f4_to_h4(acc[i][1]);
        }
    }
}

// out[d] = bias + hw[d]*dinv[d]^2 + sum_e hw16[src(e)] * wnorm(e)   (f32 acc)
// TPD = DO/4 lanes/dest, each lane covers 4 cols (8B f16 gather). Unroll x8.
template <int DO, bool RELU>
__global__ __launch_bounds__(256) void agg_kernel(const __half* __restrict__ hw,
                                                  const int* __restrict__ offsets,
                                                  const int2* __restrict__ edges,
                                                  const float* __restrict__ dinv,
                                                  const float* __restrict__ bias,
                                                  float* __restrict__ out, int n) {
    constexpr int TPD = DO / 4;            // lanes per dest
    constexpr int DPB = 256 / TPD;         // dests per block
    int d = blockIdx.x * DPB + threadIdx.x / TPD;
    int j = threadIdx.x % TPD;             // 4-col chunk index
    if (d >= n) return;

    const float2* hw2 = (const float2*)hw; // 4 halves per unit
    int beg = offsets[d];
    int end = offsets[d + 1];
    float di = dinv[d];
    float sw = di * di;

    float4 b4 = ((const float4*)bias)[j];
    float4 self = h4_to_f4(hw2[(size_t)d * TPD + j]);
    float4 acc;
    acc.x = b4.x + self.x * sw;
    acc.y = b4.y + self.y * sw;
    acc.z = b4.z + self.z * sw;
    acc.w = b4.w + self.w * sw;

    int e = beg;
    #define EDGE_FMA(EE) do {                                            \
        int2 er = edges[EE];                                             \
        float w = __int_as_float(er.y);                                  \
        float4 v = h4_to_f4(hw2[(size_t)er.x * TPD + j]);                \
        acc.x += v.x * w; acc.y += v.y * w;                              \
        acc.z += v.z * w; acc.w += v.w * w;                              \
    } while (0)

    for (; e + 8 <= end; e += 8) {
        int2 r0 = edges[e + 0], r1 = edges[e + 1], r2 = edges[e + 2], r3 = edges[e + 3];
        int2 r4 = edges[e + 4], r5 = edges[e + 5], r6 = edges[e + 6], r7 = edges[e + 7];
        float4 v0 = h4_to_f4(hw2[(size_t)r0.x * TPD + j]);
        float4 v1 = h4_to_f4(hw2[(size_t)r1.x * TPD + j]);
        float4 v2 = h4_to_f4(hw2[(size_t)r2.x * TPD + j]);
        float4 v3 = h4_to_f4(hw2[(size_t)r3.x * TPD + j]);
        float4 v4 = h4_to_f4(hw2[(size_t)r4.x * TPD + j]);
        float4 v5 = h4_to_f4(hw2[(size_t)r5.x * TPD + j]);
        float4 v6 = h4_to_f4(hw2[(size_t)r6.x * TPD + j]);
        float4 v7 = h4_to_f4(hw2[(size_t)r7.x * TPD + j]);
        float w0 = __int_as_float(r0.y), w1 = __int_as_float(r1.y);
        float w2 = __int_as_float(r2.y), w3 = __int_as_float(r3.y);
        float w4 = __int_as_float(r4.y), w5 = __int_as_float(r5.y);
        float w6 = __int_as_float(r6.y), w7 = __int_as_float(r7.y);
        acc.x += v0.x * w0; acc.y += v0.y * w0; acc.z += v0.z * w0; acc.w += v0.w * w0;
        acc.x += v1.x * w1; acc.y += v1.y * w1; acc.z += v1.z * w1; acc.w += v1.w * w1;
        acc.x += v2.x * w2; acc.y += v2.y * w2; acc.z += v2.z * w2; acc.w += v2.w * w2;
        acc.x += v3.x * w3; acc.y += v3.y * w3; acc.z += v3.z * w3; acc.w += v3.w * w3;
        acc.x += v4.x * w4; acc.y += v4.y * w4; acc.z += v4.z * w4; acc.w += v4.w * w4;
        acc.x += v5.x * w5; acc.y += v5.y * w5; acc.z += v5.z * w5; acc.w += v5.w * w5;
        acc.x += v6.x * w6; acc.y += v6.y * w6; acc.z += v6.z * w6; acc.w += v6.w * w6;
        acc.x += v7.x * w7; acc.y += v7.y * w7; acc.z += v7.z * w7; acc.w += v7.w * w7;
    }
    for (; e + 4 <= end; e += 4) {
        int2 r0 = edges[e + 0], r1 = edges[e + 1], r2 = edges[e + 2], r3 = edges[e + 3];
        float4 v0 = h4_to_f4(hw2[(size_t)r0.x * TPD + j]);
        float4 v1 = h4_to_f4(hw2[(size_t)r1.x * TPD + j]);
        float4 v2 = h4_to_f4(hw2[(size_t)r2.x * TPD + j]);
        float4 v3 = h4_to_f4(hw2[(size_t)r3.x * TPD + j]);
        float w0 = __int_as_float(r0.y), w1 = __int_as_float(r1.y);
        float w2 = __int_as_float(r2.y), w3 = __int_as_float(r3.y);
        acc.x += v0.x * w0; acc.y += v0.y * w0; acc.z += v0.z * w0; acc.w += v0.w * w0;
        acc.x += v1.x * w1; acc.y += v1.y * w1; acc.z += v1.z * w1; acc.w += v1.w * w1;
        acc.x += v2.x * w2; acc.y += v2.y * w2; acc.z += v2.z * w2; acc.w += v2.w * w2;
        acc.x += v3.x * w3; acc.y += v3.y * w3; acc.z += v3.z * w3; acc.w += v3.w * w3;
    }
    for (; e < end; ++e) EDGE_FMA(e);
    #undef EDGE_FMA

    if (RELU) {
        acc.x = fmaxf(acc.x, 0.f); acc.y = fmaxf(acc.y, 0.f);
        acc.z = fmaxf(acc.z, 0.f); acc.w = fmaxf(acc.w, 0.f);
    }
    ((float4*)out)[(size_t)d * TPD + j] = acc;
}

extern "C" void kernel_launch(void* const* d_in, const int* in_sizes, int n_in,
                              void* d_out, int out_size, void* d_ws, size_t ws_size,
                              hipStream_t stream) {
    const float* x  = (const float*)d_in[0];
    const float* W1 = (const float*)d_in[1];
    const float* b1 = (const float*)d_in[2];
    const float* W2 = (const float*)d_in[3];
    const float* b2 = (const float*)d_in[4];
    const float* W3 = (const float*)d_in[5];
    const float* b3 = (const float*)d_in[6];
    const int*   ei = (const int*)d_in[7];

    const int N = in_sizes[0] / 128;
    const int E = in_sizes[7] / 2;
    const int* rowi = ei;       // edge_index[0] = sources
    const int* coli = ei + E;   // edge_index[1] = targets

    float* out = (float*)d_out;

    // workspace carve-up (256B aligned)
    char* ws = (char*)d_ws;
    size_t off = 0;
    auto alloc = [&](size_t bytes) -> void* {
        void* p = ws + off;
        off = (off + bytes + 255) & ~(size_t)255;
        return p;
    };
    const int NB = (N + 255) / 256;        // scan blocks (196 for N=50000)
    float* dinv     = (float*)alloc((size_t)N * 4);
    int*   counts   = (int*)  alloc((size_t)N * 4);
    int*   offsets  = (int*)  alloc((size_t)(N + 1) * 4);
    int*   cursor   = (int*)  alloc((size_t)N * 4);
    int*   blocksum = (int*)  alloc((size_t)NB * 4);
    int*   blockoff = (int*)  alloc((size_t)NB * 4);
    int2*  edges    = (int2*) alloc((size_t)E * 8);
    __half* hw16    = (__half*)alloc((size_t)N * 128 * 2);
    float* hbuf     = (float*)alloc((size_t)N * 128 * 4);

    // ---- degree / norm / CSR ----
    hipMemsetAsync(counts, 0, (size_t)N * 4, stream);
    count_edges_kernel<<<(E + 255) / 256, 256, 0, stream>>>(coli, counts, E);
    block_sum_kernel<<<NB, 256, 0, stream>>>(counts, blocksum, N);
    scan_sums_kernel<<<1, 256, 0, stream>>>(blocksum, blockoff, offsets, NB, N);
    write_offsets_kernel<<<NB, 256, 0, stream>>>(counts, blockoff, offsets, cursor, dinv, N);
    fill_csr_kernel<<<(E + 255) / 256, 256, 0, stream>>>(rowi, coli, offsets, cursor, dinv, edges, E);

    // ---- layer 1: hw16 = f16(x @ W1); h = relu(agg(hw16) + b1) ----
    gemm_kernel<128><<<(N + 127) / 128, 256, 0, stream>>>(x, W1, hw16, N);
    agg_kernel<128, true><<<(N + 7) / 8, 256, 0, stream>>>(hw16, offsets, edges, dinv, b1, hbuf, N);

    // ---- layer 2 ----
    gemm_kernel<128><<<(N + 127) / 128, 256, 0, stream>>>(hbuf, W2, hw16, N);
    agg_kernel<128, true><<<(N + 7) / 8, 256, 0, stream>>>(hw16, offsets, edges, dinv, b2, hbuf, N);

    // ---- layer 3 (no relu), width 64, write d_out ----
    gemm_kernel<64><<<(N + 255) / 256, 256, 0, stream>>>(hbuf, W3, hw16, N);
    agg_kernel<64, false><<<(N + 15) / 16, 256, 0, stream>>>(hw16, offsets, edges, dinv, b3, out, N);
}